// Round 1
// baseline (1453.079 us; speedup 1.0000x reference)
//
#include <hip/hip_runtime.h>
#include <cstddef>

#define L_SEQ 2048
#define CDIM  1024
#define NH    16
#define HD    64

// ======================================================================
// Kernel 1: fused QKV GEMM + RoPE + scatter.
// x:(4096,1024)  w:(1024,3072)  freqs:(2048,32,2)
// Writes Q (rope'd, pre-scaled by 1/8), K (rope'd), V into (B,NH,L,HD).
// 128x128 tile, BK=16, 256 threads, 8x8 microtile.
// ======================================================================
__global__ __launch_bounds__(256) void qkv_rope_gemm(
    const float* __restrict__ x, const float* __restrict__ w,
    const float* __restrict__ freqs,
    float* __restrict__ Qb, float* __restrict__ Kb, float* __restrict__ Vb)
{
    constexpr int BM = 128, BN = 128, BK = 16;
    __shared__ float As[BK][BM + 4];   // [k][m] (transposed on load)
    __shared__ float Bs[BK][BN + 4];   // [k][n]
    const int tid = threadIdx.x;
    const int tx = tid & 15, ty = tid >> 4;
    const int m0 = blockIdx.y * BM;
    const int n0 = blockIdx.x * BN;

    float acc[8][8];
#pragma unroll
    for (int i = 0; i < 8; ++i)
#pragma unroll
        for (int j = 0; j < 8; ++j) acc[i][j] = 0.f;

    for (int k0 = 0; k0 < CDIM; k0 += BK) {
#pragma unroll
        for (int i = 0; i < 2; ++i) {
            int idx = tid * 2 + i;           // 0..511
            int row = idx >> 2, kq = idx & 3;
            float4 av = *(const float4*)(x + (m0 + row) * CDIM + k0 + kq * 4);
            As[kq * 4 + 0][row] = av.x;
            As[kq * 4 + 1][row] = av.y;
            As[kq * 4 + 2][row] = av.z;
            As[kq * 4 + 3][row] = av.w;
        }
#pragma unroll
        for (int i = 0; i < 2; ++i) {
            int idx = tid + i * 256;         // 0..511
            int row = idx >> 5, c4 = idx & 31;
            *(float4*)&Bs[row][c4 * 4] =
                *(const float4*)(w + (k0 + row) * (3 * CDIM) + n0 + c4 * 4);
        }
        __syncthreads();
#pragma unroll
        for (int kk = 0; kk < BK; ++kk) {
            float a[8], b[8];
            *(float4*)&a[0] = *(const float4*)&As[kk][ty * 8];
            *(float4*)&a[4] = *(const float4*)&As[kk][ty * 8 + 4];
            *(float4*)&b[0] = *(const float4*)&Bs[kk][tx * 8];
            *(float4*)&b[4] = *(const float4*)&Bs[kk][tx * 8 + 4];
#pragma unroll
            for (int i = 0; i < 8; ++i)
#pragma unroll
                for (int j = 0; j < 8; ++j)
                    acc[i][j] = fmaf(a[i], b[j], acc[i][j]);
        }
        __syncthreads();
    }

    // epilogue: rope (Q,K), scale (Q only), scatter to (B,NH,L,HD)
    const int region = n0 >> 10;          // 0=Q 1=K 2=V (blockIdx.x/8)
    const int cc = (n0 & 1023) + tx * 8;  // column within region
    const int h  = cc >> 6;
    const int d0 = cc & 63;               // multiple of 8, no head crossing
    float* dst = (region == 0) ? Qb : (region == 1) ? Kb : Vb;
    const float qs = (region == 0) ? 0.125f : 1.0f;  // HD^-0.5 folded into Q

#pragma unroll
    for (int i = 0; i < 8; ++i) {
        int m = m0 + ty * 8 + i;
        int bb = m >> 11;
        int l  = m & (L_SEQ - 1);
        float v[8];
#pragma unroll
        for (int j = 0; j < 8; ++j) v[j] = acc[i][j];
        if (region < 2) {
            const float* fr = freqs + l * HD + d0;   // (L,32,2) flat: l*64 + d
            float f[8];
            *(float4*)&f[0] = *(const float4*)(fr);
            *(float4*)&f[4] = *(const float4*)(fr + 4);
#pragma unroll
            for (int p = 0; p < 4; ++p) {
                float t0 = v[2 * p], t1 = v[2 * p + 1];
                v[2 * p]     = (t0 * f[2 * p] - t1 * f[2 * p + 1]) * qs;
                v[2 * p + 1] = (t1 * f[2 * p] + t0 * f[2 * p + 1]) * qs;
            }
        }
        float* o = dst + (size_t)((bb * NH + h) * L_SEQ + l) * HD + d0;
        *(float4*)(o)     = make_float4(v[0], v[1], v[2], v[3]);
        *(float4*)(o + 4) = make_float4(v[4], v[5], v[6], v[7]);
    }
}

// ======================================================================
// Kernel 2: flash attention with additive bias, fp32.
// grid (L/64, NH, B), block 256.  Per block: 64 q-rows, loop 64-wide kv tiles.
// LDS: Qt (Q^T), KP (K^T, later aliased as P), Vsh.  52 KB -> 3 blocks/CU.
// Thread (ty,tx): owns S rows ty*4..+3, cols tx*4..+3; O d-slice tx*4..+3.
// ======================================================================
__global__ __launch_bounds__(256) void attn_fused(
    const float* __restrict__ Qg, const float* __restrict__ Kg,
    const float* __restrict__ Vg, const float* __restrict__ bias,
    float* __restrict__ Ag)
{
    __shared__ float Qt[HD][68];    // [d][q-row]
    __shared__ float KP[HD][68];    // [d][kv-row], reused as P[q-row][kv-col]
    __shared__ float Vsh[64][68];   // [kv-row][d]
    const int tid = threadIdx.x;
    const int tx = tid & 15, ty = tid >> 4;
    const int q0 = blockIdx.x * 64;
    const int h  = blockIdx.y;
    const int b  = blockIdx.z;
    const float* Qp = Qg + (size_t)((b * NH + h) * L_SEQ + q0) * HD;
    const float* Kp = Kg + (size_t)((b * NH + h) * L_SEQ) * HD;
    const float* Vp = Vg + (size_t)((b * NH + h) * L_SEQ) * HD;
    const float* bp = bias + (size_t)(h * L_SEQ + q0) * L_SEQ;

    // load Q tile transposed (once)
#pragma unroll
    for (int i = 0; i < 4; ++i) {
        int idx = tid + i * 256;        // 0..1023
        int row = idx >> 4, q4 = idx & 15;
        float4 qv = *(const float4*)(Qp + row * HD + q4 * 4);
        Qt[q4 * 4 + 0][row] = qv.x;
        Qt[q4 * 4 + 1][row] = qv.y;
        Qt[q4 * 4 + 2][row] = qv.z;
        Qt[q4 * 4 + 3][row] = qv.w;
    }

    float m_run[4], l_run[4], oacc[4][4];
#pragma unroll
    for (int i = 0; i < 4; ++i) {
        m_run[i] = -1e30f;
        l_run[i] = 0.f;
#pragma unroll
        for (int j = 0; j < 4; ++j) oacc[i][j] = 0.f;
    }

    for (int kt = 0; kt < L_SEQ / 64; ++kt) {
        const int k0 = kt * 64;
        __syncthreads();   // previous PV done; KP/Vsh free
#pragma unroll
        for (int i = 0; i < 4; ++i) {
            int idx = tid + i * 256;
            int row = idx >> 4, q4 = idx & 15;
            float4 kv = *(const float4*)(Kp + (k0 + row) * HD + q4 * 4);
            KP[q4 * 4 + 0][row] = kv.x;
            KP[q4 * 4 + 1][row] = kv.y;
            KP[q4 * 4 + 2][row] = kv.z;
            KP[q4 * 4 + 3][row] = kv.w;
            float4 vv = *(const float4*)(Vp + (k0 + row) * HD + q4 * 4);
            *(float4*)&Vsh[row][q4 * 4] = vv;
        }
        float4 bia[4];
#pragma unroll
        for (int i = 0; i < 4; ++i)
            bia[i] = *(const float4*)(bp + (ty * 4 + i) * L_SEQ + k0 + tx * 4);
        __syncthreads();

        // S = Q*K^T (scale pre-folded into Q) + bias
        float s[4][4];
        s[0][0]=bia[0].x; s[0][1]=bia[0].y; s[0][2]=bia[0].z; s[0][3]=bia[0].w;
        s[1][0]=bia[1].x; s[1][1]=bia[1].y; s[1][2]=bia[1].z; s[1][3]=bia[1].w;
        s[2][0]=bia[2].x; s[2][1]=bia[2].y; s[2][2]=bia[2].z; s[2][3]=bia[2].w;
        s[3][0]=bia[3].x; s[3][1]=bia[3].y; s[3][2]=bia[3].z; s[3][3]=bia[3].w;
#pragma unroll 8
        for (int kk = 0; kk < HD; ++kk) {
            float4 a  = *(const float4*)&Qt[kk][ty * 4];
            float4 bv = *(const float4*)&KP[kk][tx * 4];
            float av[4] = {a.x, a.y, a.z, a.w};
            float bb2[4] = {bv.x, bv.y, bv.z, bv.w};
#pragma unroll
            for (int i = 0; i < 4; ++i)
#pragma unroll
                for (int j = 0; j < 4; ++j)
                    s[i][j] = fmaf(av[i], bb2[j], s[i][j]);
        }

        // online softmax: row reduce across the 16 tx threads (lanes 0..15)
        float tm[4], rs[4], p[4][4];
#pragma unroll
        for (int i = 0; i < 4; ++i)
            tm[i] = fmaxf(fmaxf(s[i][0], s[i][1]), fmaxf(s[i][2], s[i][3]));
#pragma unroll
        for (int off = 1; off < 16; off <<= 1)
#pragma unroll
            for (int i = 0; i < 4; ++i)
                tm[i] = fmaxf(tm[i], __shfl_xor(tm[i], off, 64));
#pragma unroll
        for (int i = 0; i < 4; ++i) {
            float mn = fmaxf(m_run[i], tm[i]);
            rs[i] = 0.f;
#pragma unroll
            for (int j = 0; j < 4; ++j) {
                p[i][j] = __expf(s[i][j] - mn);
                rs[i] += p[i][j];
            }
            tm[i] = mn;   // reuse tm as m_new
        }
#pragma unroll
        for (int off = 1; off < 16; off <<= 1)
#pragma unroll
            for (int i = 0; i < 4; ++i)
                rs[i] += __shfl_xor(rs[i], off, 64);
#pragma unroll
        for (int i = 0; i < 4; ++i) {
            float fct = __expf(m_run[i] - tm[i]);
            l_run[i] = l_run[i] * fct + rs[i];
            m_run[i] = tm[i];
#pragma unroll
            for (int j = 0; j < 4; ++j) oacc[i][j] *= fct;
        }

        __syncthreads();   // all S-phase reads of KP done
        // stage P into KP (as [q-row][kv-col])
#pragma unroll
        for (int i = 0; i < 4; ++i)
            *(float4*)&KP[ty * 4 + i][tx * 4] =
                make_float4(p[i][0], p[i][1], p[i][2], p[i][3]);
        __syncthreads();

        // O += P * V   (thread owns d-slice tx*4..+3)
#pragma unroll 4
        for (int jc = 0; jc < 16; ++jc) {
            float4 v0 = *(const float4*)&Vsh[jc * 4 + 0][tx * 4];
            float4 v1 = *(const float4*)&Vsh[jc * 4 + 1][tx * 4];
            float4 v2 = *(const float4*)&Vsh[jc * 4 + 2][tx * 4];
            float4 v3 = *(const float4*)&Vsh[jc * 4 + 3][tx * 4];
#pragma unroll
            for (int i = 0; i < 4; ++i) {
                float4 pr = *(const float4*)&KP[ty * 4 + i][jc * 4];
                oacc[i][0] = fmaf(pr.x, v0.x, oacc[i][0]);
                oacc[i][1] = fmaf(pr.x, v0.y, oacc[i][1]);
                oacc[i][2] = fmaf(pr.x, v0.z, oacc[i][2]);
                oacc[i][3] = fmaf(pr.x, v0.w, oacc[i][3]);
                oacc[i][0] = fmaf(pr.y, v1.x, oacc[i][0]);
                oacc[i][1] = fmaf(pr.y, v1.y, oacc[i][1]);
                oacc[i][2] = fmaf(pr.y, v1.z, oacc[i][2]);
                oacc[i][3] = fmaf(pr.y, v1.w, oacc[i][3]);
                oacc[i][0] = fmaf(pr.z, v2.x, oacc[i][0]);
                oacc[i][1] = fmaf(pr.z, v2.y, oacc[i][1]);
                oacc[i][2] = fmaf(pr.z, v2.z, oacc[i][2]);
                oacc[i][3] = fmaf(pr.z, v2.w, oacc[i][3]);
                oacc[i][0] = fmaf(pr.w, v3.x, oacc[i][0]);
                oacc[i][1] = fmaf(pr.w, v3.y, oacc[i][1]);
                oacc[i][2] = fmaf(pr.w, v3.z, oacc[i][2]);
                oacc[i][3] = fmaf(pr.w, v3.w, oacc[i][3]);
            }
        }
    }

    // epilogue: normalize, store to (B*L, C) with col = h*64 + d
#pragma unroll
    for (int i = 0; i < 4; ++i) {
        float inv = 1.0f / l_run[i];
        float* o = Ag + (size_t)(b * L_SEQ + q0 + ty * 4 + i) * CDIM + h * HD + tx * 4;
        *(float4*)o = make_float4(oacc[i][0] * inv, oacc[i][1] * inv,
                                  oacc[i][2] * inv, oacc[i][3] * inv);
    }
}

// ======================================================================
// Kernel 3: output projection GEMM + bias.  A:(4096,1024) w:(1024,1024)
// ======================================================================
__global__ __launch_bounds__(256) void proj_gemm(
    const float* __restrict__ A, const float* __restrict__ w,
    const float* __restrict__ bprj, float* __restrict__ out)
{
    constexpr int BM = 128, BN = 128, BK = 16;
    __shared__ float As[BK][BM + 4];
    __shared__ float Bs[BK][BN + 4];
    const int tid = threadIdx.x;
    const int tx = tid & 15, ty = tid >> 4;
    const int m0 = blockIdx.y * BM;
    const int n0 = blockIdx.x * BN;

    float acc[8][8];
#pragma unroll
    for (int i = 0; i < 8; ++i)
#pragma unroll
        for (int j = 0; j < 8; ++j) acc[i][j] = 0.f;

    for (int k0 = 0; k0 < CDIM; k0 += BK) {
#pragma unroll
        for (int i = 0; i < 2; ++i) {
            int idx = tid * 2 + i;
            int row = idx >> 2, kq = idx & 3;
            float4 av = *(const float4*)(A + (m0 + row) * CDIM + k0 + kq * 4);
            As[kq * 4 + 0][row] = av.x;
            As[kq * 4 + 1][row] = av.y;
            As[kq * 4 + 2][row] = av.z;
            As[kq * 4 + 3][row] = av.w;
        }
#pragma unroll
        for (int i = 0; i < 2; ++i) {
            int idx = tid + i * 256;
            int row = idx >> 5, c4 = idx & 31;
            *(float4*)&Bs[row][c4 * 4] =
                *(const float4*)(w + (k0 + row) * CDIM + n0 + c4 * 4);
        }
        __syncthreads();
#pragma unroll
        for (int kk = 0; kk < BK; ++kk) {
            float a[8], b[8];
            *(float4*)&a[0] = *(const float4*)&As[kk][ty * 8];
            *(float4*)&a[4] = *(const float4*)&As[kk][ty * 8 + 4];
            *(float4*)&b[0] = *(const float4*)&Bs[kk][tx * 8];
            *(float4*)&b[4] = *(const float4*)&Bs[kk][tx * 8 + 4];
#pragma unroll
            for (int i = 0; i < 8; ++i)
#pragma unroll
                for (int j = 0; j < 8; ++j)
                    acc[i][j] = fmaf(a[i], b[j], acc[i][j]);
        }
        __syncthreads();
    }

    float bb[8];
    *(float4*)&bb[0] = *(const float4*)(bprj + n0 + tx * 8);
    *(float4*)&bb[4] = *(const float4*)(bprj + n0 + tx * 8 + 4);
#pragma unroll
    for (int i = 0; i < 8; ++i) {
        int m = m0 + ty * 8 + i;
        float* o = out + (size_t)m * CDIM + n0 + tx * 8;
        *(float4*)(o)     = make_float4(acc[i][0] + bb[0], acc[i][1] + bb[1],
                                        acc[i][2] + bb[2], acc[i][3] + bb[3]);
        *(float4*)(o + 4) = make_float4(acc[i][4] + bb[4], acc[i][5] + bb[5],
                                        acc[i][6] + bb[6], acc[i][7] + bb[7]);
    }
}

// ======================================================================
extern "C" void kernel_launch(void* const* d_in, const int* in_sizes, int n_in,
                              void* d_out, int out_size, void* d_ws, size_t ws_size,
                              hipStream_t stream) {
    const float* x     = (const float*)d_in[0];
    const float* freqs = (const float*)d_in[1];
    const float* bias  = (const float*)d_in[2];
    const float* w_qkv = (const float*)d_in[3];
    const float* w_prj = (const float*)d_in[4];
    const float* b_prj = (const float*)d_in[5];
    float* out = (float*)d_out;

    const size_t per_buf = (size_t)2 * NH * L_SEQ * HD;  // 4,194,304 floats
    float* Qb = (float*)d_ws;
    float* Kb = Qb + per_buf;
    float* Vb = Kb + per_buf;
    float* Ab = Vb + per_buf;   // attention output, (B*L, C)

    // 1) QKV + RoPE:  grid (N/128=24, M/128=32)
    qkv_rope_gemm<<<dim3(24, 32), 256, 0, stream>>>(x, w_qkv, freqs, Qb, Kb, Vb);
    // 2) flash attention with bias: grid (L/64=32, NH=16, B=2)
    attn_fused<<<dim3(32, NH, 2), 256, 0, stream>>>(Qb, Kb, Vb, bias, Ab);
    // 3) projection: grid (N/128=8, M/128=32)
    proj_gemm<<<dim3(8, 32), 256, 0, stream>>>(Ab, w_prj, b_prj, out);
}

// Round 2
// 534.298 us; speedup vs baseline: 2.7196x; 2.7196x over previous
//
#include <hip/hip_runtime.h>
#include <hip/hip_bf16.h>
#include <cstddef>

#define L_SEQ 2048
#define CDIM  1024
#define NH    16
#define HD    64

typedef __attribute__((ext_vector_type(8))) short bf16x8;
typedef __attribute__((ext_vector_type(4))) float f32x4;

typedef __attribute__((address_space(3))) unsigned int lds_uint;
typedef const __attribute__((address_space(1))) unsigned int glob_uint;

__device__ __forceinline__ void gll16(const void* g, void* l) {
    __builtin_amdgcn_global_load_lds((glob_uint*)g, (lds_uint*)l, 16, 0, 0);
}
__device__ __forceinline__ short f2bf(float f) {
    __hip_bfloat16 h = __float2bfloat16(f);
    return *reinterpret_cast<short*>(&h);
}
__device__ __forceinline__ float bf2f(short s) {
    __hip_bfloat16 h = *reinterpret_cast<__hip_bfloat16*>(&s);
    return __bfloat162float(h);
}

// ======================================================================
// cast fp32 -> bf16, 8 elems/thread
// ======================================================================
__global__ __launch_bounds__(256) void cast_bf16(
    const float* __restrict__ src, short* __restrict__ dst, int n8)
{
    int t = blockIdx.x * 256 + threadIdx.x;
    if (t >= n8) return;
    float4 a = ((const float4*)src)[t * 2];
    float4 b = ((const float4*)src)[t * 2 + 1];
    short tmp[8] = { f2bf(a.x), f2bf(a.y), f2bf(a.z), f2bf(a.w),
                     f2bf(b.x), f2bf(b.y), f2bf(b.z), f2bf(b.w) };
    ((uint4*)dst)[t] = *(uint4*)tmp;
}

// ======================================================================
// transpose-cast: W (K x N) fp32 -> WT (N x K) bf16.  64x64 LDS tile.
// ======================================================================
__global__ __launch_bounds__(256) void transpose_cast(
    const float* __restrict__ W, short* __restrict__ WT, int K, int N)
{
    __shared__ float t[64][65];
    const int n0 = blockIdx.x * 64, k0 = blockIdx.y * 64;
    const int tid = threadIdx.x;
#pragma unroll
    for (int j = 0; j < 4; ++j) {
        int e = tid + j * 256;          // 0..1023
        int r = e >> 4, c4 = e & 15;
        *(float4*)&t[r][c4 * 4] = *(const float4*)(W + (size_t)(k0 + r) * N + n0 + c4 * 4);
    }
    __syncthreads();
#pragma unroll
    for (int j = 0; j < 2; ++j) {
        int e = tid + j * 256;          // 0..511
        int nr = e >> 3, c8 = (e & 7) * 8;
        short tmp[8];
#pragma unroll
        for (int i = 0; i < 8; ++i) tmp[i] = f2bf(t[c8 + i][nr]);
        *(uint4*)(WT + (size_t)(n0 + nr) * K + k0 + c8) = *(uint4*)tmp;
    }
}

// ======================================================================
// QKV GEMM bf16 MFMA (m97 pattern): A (4096,1024), BT (3072,1024).
// Epilogue scatters bf16 to Q,K (B,H,L,D) and V^T (B,H,D,L). No rope here.
// ======================================================================
__global__ __launch_bounds__(256) void gemm_qkv(
    const short* __restrict__ A, const short* __restrict__ BT,
    short* __restrict__ Qb, short* __restrict__ Kb, short* __restrict__ Vt)
{
    __shared__ short As[128 * 32];
    __shared__ short Bs[128 * 32];
    const int tid = threadIdx.x;
    const int w = tid >> 6, lane = tid & 63;
    const int m0 = blockIdx.y * 128, n0 = blockIdx.x * 128;
    const int K = CDIM;
    const int rsub = lane >> 2;          // 0..15
    const int kcol = (lane & 3) * 8;     // 0,8,16,24
    f32x4 acc[4][4] = {};

    for (int k0 = 0; k0 < K; k0 += 32) {
#pragma unroll
        for (int seg = 0; seg < 2; ++seg) {
            int r = w * 32 + seg * 16 + rsub;
            gll16(A  + (size_t)(m0 + r) * K + k0 + kcol, &As[(w * 32 + seg * 16) * 32]);
            gll16(BT + (size_t)(n0 + r) * K + k0 + kcol, &Bs[(w * 32 + seg * 16) * 32]);
        }
        __syncthreads();
        bf16x8 af[4], bfr[4];
#pragma unroll
        for (int i = 0; i < 4; ++i) {
            af[i]  = *(const bf16x8*)&As[((w >> 1) * 64 + i * 16 + (lane & 15)) * 32 + (lane >> 4) * 8];
            bfr[i] = *(const bf16x8*)&Bs[((w & 1)  * 64 + i * 16 + (lane & 15)) * 32 + (lane >> 4) * 8];
        }
#pragma unroll
        for (int i = 0; i < 4; ++i)
#pragma unroll
            for (int j = 0; j < 4; ++j)
                acc[i][j] = __builtin_amdgcn_mfma_f32_16x16x32_bf16(af[i], bfr[j], acc[i][j], 0, 0, 0);
        __syncthreads();
    }

    const int region = n0 >> 10;   // 0=Q 1=K 2=V, uniform per block
    const int wr = w >> 1, wc = w & 1;
    const int crow = (lane >> 4) * 4, ccol = lane & 15;
#pragma unroll
    for (int i = 0; i < 4; ++i)
#pragma unroll
        for (int j = 0; j < 4; ++j) {
            int n = n0 + wc * 64 + j * 16 + ccol;
            int cc = n & 1023, h = cc >> 6, d = cc & 63;
#pragma unroll
            for (int r = 0; r < 4; ++r) {
                int m = m0 + wr * 64 + i * 16 + crow + r;
                int bb = m >> 11, l = m & (L_SEQ - 1);
                short v = f2bf(acc[i][j][r]);
                if (region == 0)
                    Qb[(size_t)((bb * NH + h) * L_SEQ + l) * HD + d] = v;
                else if (region == 1)
                    Kb[(size_t)((bb * NH + h) * L_SEQ + l) * HD + d] = v;
                else
                    Vt[(size_t)((bb * NH + h) * HD + d) * L_SEQ + l] = v;
            }
        }
}

// ======================================================================
// RoPE in place on Q (scaled 1/8) and K, (B,H,L,D) bf16. 8 elems/thread.
// blockIdx.y: 0 = Q, 1 = K.
// ======================================================================
__global__ __launch_bounds__(256) void rope_kernel(
    short* __restrict__ Qb, short* __restrict__ Kb, const float* __restrict__ freqs)
{
    int t = blockIdx.x * 256 + threadIdx.x;          // 0..524287
    short* P = blockIdx.y ? Kb : Qb;
    const float qs = blockIdx.y ? 1.0f : 0.125f;
    const int d0 = (t * 8) & (HD - 1);
    const int l  = (t >> 3) & (L_SEQ - 1);
    uint4 raw = ((uint4*)P)[t];
    short* s = (short*)&raw;
    const float* fr = freqs + l * HD + d0;
    float f[8];
    *(float4*)&f[0] = *(const float4*)fr;
    *(float4*)&f[4] = *(const float4*)(fr + 4);
    short outv[8];
#pragma unroll
    for (int p = 0; p < 4; ++p) {
        float a = bf2f(s[2 * p]), b = bf2f(s[2 * p + 1]);
        outv[2 * p]     = f2bf((a * f[2 * p] - b * f[2 * p + 1]) * qs);
        outv[2 * p + 1] = f2bf((b * f[2 * p] + a * f[2 * p + 1]) * qs);
    }
    ((uint4*)P)[t] = *(uint4*)outv;
}

// ======================================================================
// Flash attention, bf16 MFMA 16x16x32, fp32 softmax, bias seeds acc.
// grid (L/64, NH, B), 256 thr = 4 waves; wave w owns q rows w*16..+16.
// ======================================================================
__global__ __launch_bounds__(256) void attn_mfma(
    const short* __restrict__ Qb, const short* __restrict__ Kb,
    const short* __restrict__ Vt, const float* __restrict__ bias,
    short* __restrict__ Ab)
{
    __shared__ short Qs[64][72];
    __shared__ short Ks[64][72];
    __shared__ short Vs[64][72];     // V^T tile: [d][k]
    __shared__ short Ps[4][16][72];  // per-wave P
    const int tid = threadIdx.x, w = tid >> 6, lane = tid & 63;
    const int q0 = blockIdx.x * 64, h = blockIdx.y, b = blockIdx.z;
    const short* Qp = Qb + (size_t)((b * NH + h) * L_SEQ + q0) * HD;
    const short* Kp = Kb + (size_t)((b * NH + h) * L_SEQ) * HD;
    const short* Vp = Vt + (size_t)((b * NH + h) * HD) * L_SEQ;
    const float* bp = bias + (size_t)h * L_SEQ * L_SEQ + (size_t)q0 * L_SEQ;

#pragma unroll
    for (int j = 0; j < 2; ++j) {
        int e = tid + j * 256;
        int r = e >> 3, c8 = (e & 7) * 8;
        *(uint4*)&Qs[r][c8] = *(const uint4*)(Qp + (size_t)r * HD + c8);
    }

    const int g = lane >> 4, c = lane & 15;
    float m_run[4], l_run[4];
    f32x4 oacc[4] = {};
#pragma unroll
    for (int r = 0; r < 4; ++r) { m_run[r] = -1e30f; l_run[r] = 0.f; }

    for (int kt = 0; kt < L_SEQ / 64; ++kt) {
        const int k0 = kt * 64;
        __syncthreads();   // prev-iter LDS reads done (also covers Qs init)
#pragma unroll
        for (int j = 0; j < 2; ++j) {
            int e = tid + j * 256;
            int r = e >> 3, c8 = (e & 7) * 8;
            *(uint4*)&Ks[r][c8] = *(const uint4*)(Kp + (size_t)(k0 + r) * HD + c8);
            *(uint4*)&Vs[r][c8] = *(const uint4*)(Vp + (size_t)r * L_SEQ + k0 + c8);
        }
        // bias seeds S accumulator
        f32x4 sacc[4];
#pragma unroll
        for (int j = 0; j < 4; ++j)
#pragma unroll
            for (int r = 0; r < 4; ++r)
                sacc[j][r] = bp[(size_t)(w * 16 + g * 4 + r) * L_SEQ + k0 + j * 16 + c];
        __syncthreads();

        // S = Q K^T + bias   (scale folded into Q by rope_kernel)
#pragma unroll
        for (int kb = 0; kb < 2; ++kb) {
            bf16x8 aq = *(const bf16x8*)&Qs[w * 16 + c][kb * 32 + g * 8];
#pragma unroll
            for (int j = 0; j < 4; ++j) {
                bf16x8 bk = *(const bf16x8*)&Ks[j * 16 + c][kb * 32 + g * 8];
                sacc[j] = __builtin_amdgcn_mfma_f32_16x16x32_bf16(aq, bk, sacc[j], 0, 0, 0);
            }
        }

        // online softmax (row = w*16 + g*4 + r, held by 16 lanes g*16..g*16+15)
        float mnew[4], pv[4][4];
#pragma unroll
        for (int r = 0; r < 4; ++r) {
            float tmv = fmaxf(fmaxf(sacc[0][r], sacc[1][r]), fmaxf(sacc[2][r], sacc[3][r]));
#pragma unroll
            for (int off = 1; off < 16; off <<= 1)
                tmv = fmaxf(tmv, __shfl_xor(tmv, off, 64));
            mnew[r] = fmaxf(m_run[r], tmv);
        }
#pragma unroll
        for (int r = 0; r < 4; ++r) {
            float acc = 0.f;
#pragma unroll
            for (int j = 0; j < 4; ++j) { pv[j][r] = __expf(sacc[j][r] - mnew[r]); acc += pv[j][r]; }
#pragma unroll
            for (int off = 1; off < 16; off <<= 1) acc += __shfl_xor(acc, off, 64);
            float fct = __expf(m_run[r] - mnew[r]);
            l_run[r] = l_run[r] * fct + acc;
            m_run[r] = mnew[r];
#pragma unroll
            for (int di = 0; di < 4; ++di) oacc[di][r] *= fct;
        }

        // stage P (bf16) into per-wave LDS
#pragma unroll
        for (int j = 0; j < 4; ++j)
#pragma unroll
            for (int r = 0; r < 4; ++r)
                Ps[w][g * 4 + r][j * 16 + c] = f2bf(pv[j][r]);
        asm volatile("" ::: "memory");   // keep ds_writes before ds_reads (same-wave LDS is in-order)

        // O += P V
#pragma unroll
        for (int kb = 0; kb < 2; ++kb) {
            bf16x8 pa = *(const bf16x8*)&Ps[w][c][kb * 32 + g * 8];
#pragma unroll
            for (int di = 0; di < 4; ++di) {
                bf16x8 vb = *(const bf16x8*)&Vs[di * 16 + c][kb * 32 + g * 8];
                oacc[di] = __builtin_amdgcn_mfma_f32_16x16x32_bf16(pa, vb, oacc[di], 0, 0, 0);
            }
        }
    }

    // epilogue: normalize, write bf16 to (B*L, C)
#pragma unroll
    for (int di = 0; di < 4; ++di)
#pragma unroll
        for (int r = 0; r < 4; ++r) {
            int m = b * L_SEQ + q0 + w * 16 + g * 4 + r;
            int col = h * HD + di * 16 + c;
            Ab[(size_t)m * CDIM + col] = f2bf(oacc[di][r] / l_run[r]);
        }
}

// ======================================================================
// proj GEMM bf16 MFMA: A (4096,1024) bf16, BT (1024,1024) bf16, +bias, fp32 out
// ======================================================================
__global__ __launch_bounds__(256) void gemm_proj(
    const short* __restrict__ A, const short* __restrict__ BT,
    const float* __restrict__ bprj, float* __restrict__ out)
{
    __shared__ short As[128 * 32];
    __shared__ short Bs[128 * 32];
    const int tid = threadIdx.x;
    const int w = tid >> 6, lane = tid & 63;
    const int m0 = blockIdx.y * 128, n0 = blockIdx.x * 128;
    const int K = CDIM;
    const int rsub = lane >> 2;
    const int kcol = (lane & 3) * 8;
    f32x4 acc[4][4] = {};

    for (int k0 = 0; k0 < K; k0 += 32) {
#pragma unroll
        for (int seg = 0; seg < 2; ++seg) {
            int r = w * 32 + seg * 16 + rsub;
            gll16(A  + (size_t)(m0 + r) * K + k0 + kcol, &As[(w * 32 + seg * 16) * 32]);
            gll16(BT + (size_t)(n0 + r) * K + k0 + kcol, &Bs[(w * 32 + seg * 16) * 32]);
        }
        __syncthreads();
        bf16x8 af[4], bfr[4];
#pragma unroll
        for (int i = 0; i < 4; ++i) {
            af[i]  = *(const bf16x8*)&As[((w >> 1) * 64 + i * 16 + (lane & 15)) * 32 + (lane >> 4) * 8];
            bfr[i] = *(const bf16x8*)&Bs[((w & 1)  * 64 + i * 16 + (lane & 15)) * 32 + (lane >> 4) * 8];
        }
#pragma unroll
        for (int i = 0; i < 4; ++i)
#pragma unroll
            for (int j = 0; j < 4; ++j)
                acc[i][j] = __builtin_amdgcn_mfma_f32_16x16x32_bf16(af[i], bfr[j], acc[i][j], 0, 0, 0);
        __syncthreads();
    }

    const int wr = w >> 1, wc = w & 1;
    const int crow = (lane >> 4) * 4, ccol = lane & 15;
#pragma unroll
    for (int i = 0; i < 4; ++i)
#pragma unroll
        for (int j = 0; j < 4; ++j) {
            int n = n0 + wc * 64 + j * 16 + ccol;
            float bv = bprj[n];
#pragma unroll
            for (int r = 0; r < 4; ++r) {
                int m = m0 + wr * 64 + i * 16 + crow + r;
                out[(size_t)m * CDIM + n] = acc[i][j][r] + bv;
            }
        }
}

// ======================================================================
extern "C" void kernel_launch(void* const* d_in, const int* in_sizes, int n_in,
                              void* d_out, int out_size, void* d_ws, size_t ws_size,
                              hipStream_t stream) {
    const float* x     = (const float*)d_in[0];
    const float* freqs = (const float*)d_in[1];
    const float* bias  = (const float*)d_in[2];
    const float* w_qkv = (const float*)d_in[3];
    const float* w_prj = (const float*)d_in[4];
    const float* b_prj = (const float*)d_in[5];
    float* out = (float*)d_out;

    short* ws = (short*)d_ws;
    short* xb     = ws;                       // 4096*1024
    short* wqkvT  = xb + 4194304;             // 3072*1024
    short* wprojT = wqkvT + 3145728;          // 1024*1024
    short* Qb     = wprojT + 1048576;         // B,H,L,D
    short* Kb     = Qb + 4194304;
    short* Vt     = Kb + 4194304;             // B,H,D,L
    short* Ab     = Vt + 4194304;             // 4096*1024

    // 1) casts
    cast_bf16<<<2048, 256, 0, stream>>>(x, xb, 524288);
    transpose_cast<<<dim3(48, 16), 256, 0, stream>>>(w_qkv, wqkvT, CDIM, 3 * CDIM);
    transpose_cast<<<dim3(16, 16), 256, 0, stream>>>(w_prj, wprojT, CDIM, CDIM);
    // 2) QKV GEMM + scatter
    gemm_qkv<<<dim3(24, 32), 256, 0, stream>>>(xb, wqkvT, Qb, Kb, Vt);
    // 3) RoPE on Q (scaled) and K
    rope_kernel<<<dim3(2048, 2), 256, 0, stream>>>(Qb, Kb, freqs);
    // 4) attention
    attn_mfma<<<dim3(32, NH, 2), 256, 0, stream>>>(Qb, Kb, Vt, bias, Ab);
    // 5) projection
    gemm_proj<<<dim3(8, 32), 256, 0, stream>>>(Ab, wprojT, b_prj, out);
}